// Round 1
// baseline (1090.780 us; speedup 1.0000x reference)
//
#include <hip/hip_runtime.h>
#include <math.h>

// ============================================================================
// Cross-covariance transformer block, all-f32 correctness-first baseline.
//
// Key derivation (raw reshape semantics):
//   Q = (v@Wq).reshape(16,B,S,8):  value at [g,b,s,h] = Qtok[tok][chan] with
//       tok = g*8192 + b*256 + s/16,  chan = (s%16)*8 + h
//   -> chunk p = g*32+b = tok/256 covers tokens [256p, 256p+256),
//      view-row (r=tok%256, j=chan/8), 8-vector = channels j*8..j*8+7.
//   Output permutation: ao[g,b,d,s] -> attn[tok2][c2] with
//       tok2 = g*8192 + r*32 + j*2 + b/16,  c2 = (b%16)*8 + d   (s = r*16+j)
//
// Pipeline (all on `stream`):
//   K1 x3 : Qn = norm8(v@Wq+bq), Kn = norm8(q@Wk+bk), V = q@Wv+bv   (f32)
//   K2    : per chunk p: scores8x8 = sum QnT*Kn * 1/sqrt(32); lower-median
//           mask (strict >); softmax -> probs[512][8][8]
//   K3    : AO = probs @ V-groups, scatter-write into permuted attn matrix
//   K4    : h = LN(v + attn@Wo + bo)
//   K5    : out = LN(h + gelu(h@W1+b1)@W2 + b2) + v      (fused FFN)
//
// ws layout (f32): Qn[16M] Kn[16M] V[16M] probs[32K]; attn reuses Qn, h
// reuses Kn.  Total ~192.1 MB.
// ============================================================================

static constexpr int  DM   = 128;
static constexpr long NTOK = 131072;                 // B*S = 32*4096
static constexpr float NORMF = 0.17677669529663687f; // 1/sqrt(32)

// ---------------------------------------------------------------------------
// K1: out[t][c] = in[t]·W[:,c] + b[c]; optional L2-normalize per 8-chan group.
// 64 tokens/block, 256 threads: thread = (token-slot ts 0..15 [4 tokens], group gr 0..15)
// ---------------------------------------------------------------------------
template<bool NORM>
__global__ __launch_bounds__(256)
void k_gemm128(const float* __restrict__ in, const float* __restrict__ W,
               const float* __restrict__ bias, float* __restrict__ out)
{
    __shared__ float Wl[128 * 132];
    __shared__ float xl[64 * 132];
    const int tid = threadIdx.x;
    const int gr  = tid & 15;
    const int ts  = tid >> 4;
    const long tok0 = (long)blockIdx.x * 64;

    const float4* W4 = (const float4*)W;
    #pragma unroll
    for (int i = 0; i < 16; ++i) {
        int e = tid + i * 256;              // float4 index over 128x32
        int k = e >> 5, c4 = e & 31;
        float4 w = W4[e];
        float* dst = &Wl[k * 132 + c4 * 4];
        dst[0] = w.x; dst[1] = w.y; dst[2] = w.z; dst[3] = w.w;
    }
    const float4* in4 = (const float4*)(in + tok0 * DM);
    #pragma unroll
    for (int i = 0; i < 8; ++i) {
        int e = tid + i * 256;              // float4 index over 64x32
        int t = e >> 5, c4 = e & 31;
        float4 xv = in4[e];
        float* dst = &xl[t * 132 + c4 * 4];
        dst[0] = xv.x; dst[1] = xv.y; dst[2] = xv.z; dst[3] = xv.w;
    }
    __syncthreads();

    float acc[4][8];
    #pragma unroll
    for (int m = 0; m < 4; ++m)
        #pragma unroll
        for (int i = 0; i < 8; ++i) acc[m][i] = 0.f;

    #pragma unroll 4
    for (int k = 0; k < 128; ++k) {
        const float4 wA = *(const float4*)&Wl[k * 132 + gr * 8];
        const float4 wB = *(const float4*)&Wl[k * 132 + gr * 8 + 4];
        #pragma unroll
        for (int m = 0; m < 4; ++m) {
            float xv = xl[(ts * 4 + m) * 132 + k];
            acc[m][0] = fmaf(xv, wA.x, acc[m][0]);
            acc[m][1] = fmaf(xv, wA.y, acc[m][1]);
            acc[m][2] = fmaf(xv, wA.z, acc[m][2]);
            acc[m][3] = fmaf(xv, wA.w, acc[m][3]);
            acc[m][4] = fmaf(xv, wB.x, acc[m][4]);
            acc[m][5] = fmaf(xv, wB.y, acc[m][5]);
            acc[m][6] = fmaf(xv, wB.z, acc[m][6]);
            acc[m][7] = fmaf(xv, wB.w, acc[m][7]);
        }
    }

    float bv[8];
    #pragma unroll
    for (int i = 0; i < 8; ++i) bv[i] = bias[gr * 8 + i];

    #pragma unroll
    for (int m = 0; m < 4; ++m) {
        float o[8];
        #pragma unroll
        for (int i = 0; i < 8; ++i) o[i] = acc[m][i] + bv[i];
        if (NORM) {
            float ss = 0.f;
            #pragma unroll
            for (int i = 0; i < 8; ++i) ss = fmaf(o[i], o[i], ss);
            float inv = 1.f / fmaxf(sqrtf(ss), 1e-12f);
            #pragma unroll
            for (int i = 0; i < 8; ++i) o[i] *= inv;
        }
        float* dst = out + (tok0 + ts * 4 + m) * DM + gr * 8;
        *(float4*)dst       = (float4){o[0], o[1], o[2], o[3]};
        *(float4*)(dst + 4) = (float4){o[4], o[5], o[6], o[7]};
    }
}

// ---------------------------------------------------------------------------
// K2: per chunk p (512 blocks): scores = sum over 4096 view-rows of qn8 x kn8,
// *NORMF, lower-median strict mask, softmax -> probs[p][8][8].
// ---------------------------------------------------------------------------
__global__ __launch_bounds__(256)
void k_scores(const float* __restrict__ Qn, const float* __restrict__ Kn,
              float* __restrict__ probs)
{
    __shared__ float red[256 * 65];
    __shared__ float part[4 * 64];
    __shared__ float sc[64];
    __shared__ float pl[64];
    const int tid = threadIdx.x;
    const long base = (long)blockIdx.x * 32768;

    float acc[64];
    #pragma unroll
    for (int i = 0; i < 64; ++i) acc[i] = 0.f;

    for (int it = 0; it < 16; ++it) {
        long pi = (long)it * 256 + tid;     // (t,j) pair; flat offset = pi*8
        const float4* q4 = (const float4*)(Qn + base + pi * 8);
        const float4* k4 = (const float4*)(Kn + base + pi * 8);
        float4 qa = q4[0], qb = q4[1], ka = k4[0], kb = k4[1];
        float qv[8] = {qa.x, qa.y, qa.z, qa.w, qb.x, qb.y, qb.z, qb.w};
        float kv[8] = {ka.x, ka.y, ka.z, ka.w, kb.x, kb.y, kb.z, kb.w};
        #pragma unroll
        for (int d = 0; d < 8; ++d)
            #pragma unroll
            for (int e = 0; e < 8; ++e)
                acc[d * 8 + e] = fmaf(qv[d], kv[e], acc[d * 8 + e]);
    }

    #pragma unroll
    for (int i = 0; i < 64; ++i) red[tid * 65 + i] = acc[i];
    __syncthreads();

    {   // 256 -> 4 partials
        int g2 = tid >> 6, e = tid & 63;
        float s = 0.f;
        for (int t = 0; t < 64; ++t) s += red[(g2 * 64 + t) * 65 + e];
        part[g2 * 64 + e] = s;
    }
    __syncthreads();
    if (tid < 64)
        sc[tid] = (part[tid] + part[64 + tid] + part[128 + tid] + part[192 + tid]) * NORMF;
    __syncthreads();

    if (tid < 8) {
        float row[8], st[8];
        #pragma unroll
        for (int e = 0; e < 8; ++e) { row[e] = sc[tid * 8 + e]; st[e] = row[e]; }
        // insertion sort (ascending); lower median = st[3]
        for (int a = 1; a < 8; ++a) {
            float v = st[a]; int b = a - 1;
            while (b >= 0 && st[b] > v) { st[b + 1] = st[b]; --b; }
            st[b + 1] = v;
        }
        float med = st[3];
        float mv[8]; float mx = -3.0e38f;
        #pragma unroll
        for (int e = 0; e < 8; ++e) {
            mv[e] = (row[e] - med > 0.f) ? row[e] : -1e30f;
            mx = fmaxf(mx, mv[e]);
        }
        float z = 0.f, ex[8];
        #pragma unroll
        for (int e = 0; e < 8; ++e) { ex[e] = expf(mv[e] - mx); z += ex[e]; }
        float iz = 1.f / z;
        #pragma unroll
        for (int e = 0; e < 8; ++e) pl[tid * 8 + e] = ex[e] * iz;
    }
    __syncthreads();
    if (tid < 64) probs[(long)blockIdx.x * 64 + tid] = pl[tid];
}

// ---------------------------------------------------------------------------
// K3: AO[t][j*8+d] = sum_e probs_p[d][e] * V[t][j*8+e]; scatter into permuted
// attn matrix. Block = 16 tokens x 16 groups (all in one chunk).
// ---------------------------------------------------------------------------
__global__ __launch_bounds__(256)
void k_ao_scatter(const float* __restrict__ V, const float* __restrict__ probs,
                  float* __restrict__ attn)
{
    __shared__ float pl[64];
    const int tid = threadIdx.x;
    const int p = blockIdx.x >> 4;
    if (tid < 64) pl[tid] = probs[(long)p * 64 + tid];
    __syncthreads();

    const long w = (long)blockIdx.x * 256 + tid;
    const long t = w >> 4;                 // global token
    const int  j = (int)(w & 15);
    const int  r = (int)(t & 255);
    const int  g = p >> 5, b = p & 31;

    const float4* v4 = (const float4*)(V + t * DM + j * 8);
    float4 va = v4[0], vb = v4[1];
    float vv[8] = {va.x, va.y, va.z, va.w, vb.x, vb.y, vb.z, vb.w};
    float ao[8];
    #pragma unroll
    for (int d = 0; d < 8; ++d) {
        float s = 0.f;
        #pragma unroll
        for (int e = 0; e < 8; ++e) s = fmaf(pl[d * 8 + e], vv[e], s);
        ao[d] = s;
    }
    const long tok2 = (long)g * 8192 + r * 32 + j * 2 + (b >> 4);
    float* dst = attn + tok2 * DM + (b & 15) * 8;
    *(float4*)dst       = (float4){ao[0], ao[1], ao[2], ao[3]};
    *(float4*)(dst + 4) = (float4){ao[4], ao[5], ao[6], ao[7]};
}

// ---------------------------------------------------------------------------
// K4: h = LN(v + attn@Wo + bo)
// ---------------------------------------------------------------------------
__global__ __launch_bounds__(256)
void k_wo_ln(const float* __restrict__ attn, const float* __restrict__ W,
             const float* __restrict__ bias, const float* __restrict__ vres,
             const float* __restrict__ lng, const float* __restrict__ lnb,
             float* __restrict__ h)
{
    __shared__ float Wl[128 * 132];
    __shared__ float xl[64 * 132];
    __shared__ float mu[64], rs[64];
    const int tid = threadIdx.x;
    const int gr  = tid & 15;
    const int ts  = tid >> 4;
    const long tok0 = (long)blockIdx.x * 64;

    const float4* W4 = (const float4*)W;
    #pragma unroll
    for (int i = 0; i < 16; ++i) {
        int e = tid + i * 256;
        int k = e >> 5, c4 = e & 31;
        float4 w = W4[e];
        float* dst = &Wl[k * 132 + c4 * 4];
        dst[0] = w.x; dst[1] = w.y; dst[2] = w.z; dst[3] = w.w;
    }
    const float4* in4 = (const float4*)(attn + tok0 * DM);
    #pragma unroll
    for (int i = 0; i < 8; ++i) {
        int e = tid + i * 256;
        int t = e >> 5, c4 = e & 31;
        float4 xv = in4[e];
        float* dst = &xl[t * 132 + c4 * 4];
        dst[0] = xv.x; dst[1] = xv.y; dst[2] = xv.z; dst[3] = xv.w;
    }
    __syncthreads();

    float acc[4][8];
    #pragma unroll
    for (int m = 0; m < 4; ++m)
        #pragma unroll
        for (int i = 0; i < 8; ++i) acc[m][i] = 0.f;

    #pragma unroll 4
    for (int k = 0; k < 128; ++k) {
        const float4 wA = *(const float4*)&Wl[k * 132 + gr * 8];
        const float4 wB = *(const float4*)&Wl[k * 132 + gr * 8 + 4];
        #pragma unroll
        for (int m = 0; m < 4; ++m) {
            float xv = xl[(ts * 4 + m) * 132 + k];
            acc[m][0] = fmaf(xv, wA.x, acc[m][0]);
            acc[m][1] = fmaf(xv, wA.y, acc[m][1]);
            acc[m][2] = fmaf(xv, wA.z, acc[m][2]);
            acc[m][3] = fmaf(xv, wA.w, acc[m][3]);
            acc[m][4] = fmaf(xv, wB.x, acc[m][4]);
            acc[m][5] = fmaf(xv, wB.y, acc[m][5]);
            acc[m][6] = fmaf(xv, wB.z, acc[m][6]);
            acc[m][7] = fmaf(xv, wB.w, acc[m][7]);
        }
    }
    __syncthreads();   // all GEMM reads of xl done before overwrite

    #pragma unroll
    for (int m = 0; m < 4; ++m) {
        const long tok = tok0 + ts * 4 + m;
        #pragma unroll
        for (int i = 0; i < 8; ++i) {
            int c = gr * 8 + i;
            xl[(ts * 4 + m) * 132 + c] = acc[m][i] + bias[c] + vres[tok * DM + c];
        }
    }
    __syncthreads();

    if (tid < 64) {
        const float* row = &xl[tid * 132];
        float s = 0.f;
        for (int c = 0; c < 128; ++c) s += row[c];
        float m_ = s * 0.0078125f;
        float vs = 0.f;
        for (int c = 0; c < 128; ++c) { float d = row[c] - m_; vs = fmaf(d, d, vs); }
        mu[tid] = m_;
        rs[tid] = rsqrtf(vs * 0.0078125f + 1e-5f);
    }
    __syncthreads();

    #pragma unroll
    for (int m = 0; m < 4; ++m) {
        int t = ts * 4 + m;
        float m_ = mu[t], r_ = rs[t];
        float o[8];
        #pragma unroll
        for (int i = 0; i < 8; ++i) {
            int c = gr * 8 + i;
            o[i] = (xl[t * 132 + c] - m_) * r_ * lng[c] + lnb[c];
        }
        float* dst = h + (tok0 + t) * DM + gr * 8;
        *(float4*)dst       = (float4){o[0], o[1], o[2], o[3]};
        *(float4*)(dst + 4) = (float4){o[4], o[5], o[6], o[7]};
    }
}

// ---------------------------------------------------------------------------
// K5: out = LN(h + gelu(h@W1+b1)@W2 + b2) + v   (fused FFN, 4 hidden slices)
// ---------------------------------------------------------------------------
__global__ __launch_bounds__(256)
void k_ffn(const float* __restrict__ h, const float* __restrict__ W1,
           const float* __restrict__ b1, const float* __restrict__ W2,
           const float* __restrict__ b2, const float* __restrict__ lng,
           const float* __restrict__ lnb, const float* __restrict__ vres,
           float* __restrict__ out)
{
    __shared__ float Wb[128 * 132];
    __shared__ float xl[64 * 132];
    __shared__ float hid[64 * 132];
    __shared__ float mu[64], rs[64];
    const int tid = threadIdx.x;
    const int gr  = tid & 15;
    const int ts  = tid >> 4;
    const long tok0 = (long)blockIdx.x * 64;

    const float4* h4 = (const float4*)(h + tok0 * DM);
    #pragma unroll
    for (int i = 0; i < 8; ++i) {
        int e = tid + i * 256;
        int t = e >> 5, c4 = e & 31;
        float4 xv = h4[e];
        float* dst = &xl[t * 132 + c4 * 4];
        dst[0] = xv.x; dst[1] = xv.y; dst[2] = xv.z; dst[3] = xv.w;
    }

    float oacc[4][8];
    #pragma unroll
    for (int m = 0; m < 4; ++m)
        #pragma unroll
        for (int i = 0; i < 8; ++i) oacc[m][i] = 0.f;

    for (int sl = 0; sl < 4; ++sl) {
        __syncthreads();   // xl staged (sl=0) / prev-slice reads of Wb,hid done
        #pragma unroll
        for (int i = 0; i < 16; ++i) {      // Wb = W1[:, sl*128 .. +128)
            int e = tid + i * 256;
            int k = e >> 5, c4 = e & 31;
            float4 w = *(const float4*)(W1 + (long)k * 512 + sl * 128 + c4 * 4);
            float* dst = &Wb[k * 132 + c4 * 4];
            dst[0] = w.x; dst[1] = w.y; dst[2] = w.z; dst[3] = w.w;
        }
        __syncthreads();

        float hacc[4][8];
        #pragma unroll
        for (int m = 0; m < 4; ++m)
            #pragma unroll
            for (int i = 0; i < 8; ++i) hacc[m][i] = 0.f;

        #pragma unroll 4
        for (int k = 0; k < 128; ++k) {
            const float4 wA = *(const float4*)&Wb[k * 132 + gr * 8];
            const float4 wB = *(const float4*)&Wb[k * 132 + gr * 8 + 4];
            #pragma unroll
            for (int m = 0; m < 4; ++m) {
                float xv = xl[(ts * 4 + m) * 132 + k];
                hacc[m][0] = fmaf(xv, wA.x, hacc[m][0]);
                hacc[m][1] = fmaf(xv, wA.y, hacc[m][1]);
                hacc[m][2] = fmaf(xv, wA.z, hacc[m][2]);
                hacc[m][3] = fmaf(xv, wA.w, hacc[m][3]);
                hacc[m][4] = fmaf(xv, wB.x, hacc[m][4]);
                hacc[m][5] = fmaf(xv, wB.y, hacc[m][5]);
                hacc[m][6] = fmaf(xv, wB.z, hacc[m][6]);
                hacc[m][7] = fmaf(xv, wB.w, hacc[m][7]);
            }
        }
        #pragma unroll
        for (int m = 0; m < 4; ++m)
            #pragma unroll
            for (int i = 0; i < 8; ++i) {
                float x = hacc[m][i] + b1[sl * 128 + gr * 8 + i];
                float gel = 0.5f * x * (1.f + erff(x * 0.70710678118654752f));
                hid[(ts * 4 + m) * 132 + gr * 8 + i] = gel;
            }
        __syncthreads();   // hid ready; Wb reads done -> restage

        #pragma unroll
        for (int i = 0; i < 16; ++i) {      // Wb = W2[sl*128 .. +128, :]
            int e = tid + i * 256;
            int kk = e >> 5, c4 = e & 31;
            float4 w = *(const float4*)(W2 + (long)(sl * 128 + kk) * 128 + c4 * 4);
            float* dst = &Wb[kk * 132 + c4 * 4];
            dst[0] = w.x; dst[1] = w.y; dst[2] = w.z; dst[3] = w.w;
        }
        __syncthreads();

        #pragma unroll 4
        for (int kk = 0; kk < 128; ++kk) {
            const float4 wA = *(const float4*)&Wb[kk * 132 + gr * 8];
            const float4 wB = *(const float4*)&Wb[kk * 132 + gr * 8 + 4];
            #pragma unroll
            for (int m = 0; m < 4; ++m) {
                float hv = hid[(ts * 4 + m) * 132 + kk];
                oacc[m][0] = fmaf(hv, wA.x, oacc[m][0]);
                oacc[m][1] = fmaf(hv, wA.y, oacc[m][1]);
                oacc[m][2] = fmaf(hv, wA.z, oacc[m][2]);
                oacc[m][3] = fmaf(hv, wA.w, oacc[m][3]);
                oacc[m][4] = fmaf(hv, wB.x, oacc[m][4]);
                oacc[m][5] = fmaf(hv, wB.y, oacc[m][5]);
                oacc[m][6] = fmaf(hv, wB.z, oacc[m][6]);
                oacc[m][7] = fmaf(hv, wB.w, oacc[m][7]);
            }
        }
    }
    __syncthreads();   // done reading hid -> reuse as t2 tile

    #pragma unroll
    for (int m = 0; m < 4; ++m)
        #pragma unroll
        for (int i = 0; i < 8; ++i) {
            int c = gr * 8 + i;
            hid[(ts * 4 + m) * 132 + c] =
                xl[(ts * 4 + m) * 132 + c] + oacc[m][i] + b2[c];
        }
    __syncthreads();

    if (tid < 64) {
        const float* row = &hid[tid * 132];
        float s = 0.f;
        for (int c = 0; c < 128; ++c) s += row[c];
        float m_ = s * 0.0078125f;
        float vs = 0.f;
        for (int c = 0; c < 128; ++c) { float d = row[c] - m_; vs = fmaf(d, d, vs); }
        mu[tid] = m_;
        rs[tid] = rsqrtf(vs * 0.0078125f + 1e-5f);
    }
    __syncthreads();

    #pragma unroll
    for (int m = 0; m < 4; ++m) {
        int t = ts * 4 + m;
        const long tok = tok0 + t;
        float m_ = mu[t], r_ = rs[t];
        float o[8];
        #pragma unroll
        for (int i = 0; i < 8; ++i) {
            int c = gr * 8 + i;
            o[i] = (hid[t * 132 + c] - m_) * r_ * lng[c] + lnb[c] + vres[tok * DM + c];
        }
        float* dst = out + tok * DM + gr * 8;
        *(float4*)dst       = (float4){o[0], o[1], o[2], o[3]};
        *(float4*)(dst + 4) = (float4){o[4], o[5], o[6], o[7]};
    }
}

// ---------------------------------------------------------------------------
extern "C" void kernel_launch(void* const* d_in, const int* in_sizes, int n_in,
                              void* d_out, int out_size, void* d_ws, size_t ws_size,
                              hipStream_t stream)
{
    const float* q   = (const float*)d_in[0];   // key/value-side input
    const float* v   = (const float*)d_in[1];   // query-side + residual input
    const float* Wq  = (const float*)d_in[2];
    const float* bq  = (const float*)d_in[3];
    const float* Wk  = (const float*)d_in[4];
    const float* bk  = (const float*)d_in[5];
    const float* Wv  = (const float*)d_in[6];
    const float* bv  = (const float*)d_in[7];
    const float* Wo  = (const float*)d_in[8];
    const float* bo  = (const float*)d_in[9];
    const float* lng = (const float*)d_in[10];
    const float* lnb = (const float*)d_in[11];
    const float* W1  = (const float*)d_in[12];
    const float* b1  = (const float*)d_in[13];
    const float* W2  = (const float*)d_in[14];
    const float* b2  = (const float*)d_in[15];
    float* out = (float*)d_out;

    float* Qn    = (float*)d_ws;                // 16,777,216 f
    float* Kn    = Qn + NTOK * 128;             // 16,777,216 f
    float* Vv    = Kn + NTOK * 128;             // 16,777,216 f
    float* probs = Vv + NTOK * 128;             // 32,768 f
    float* attn  = Qn;                          // reuse (Qn dead after K2)
    float* hbuf  = Kn;                          // reuse (Kn dead after K2)

    dim3 blk(256);
    // Q from v (query side), K/V from q
    k_gemm128<true ><<<2048, blk, 0, stream>>>(v, Wq, bq, Qn);
    k_gemm128<true ><<<2048, blk, 0, stream>>>(q, Wk, bk, Kn);
    k_gemm128<false><<<2048, blk, 0, stream>>>(q, Wv, bv, Vv);
    k_scores   <<<512,  blk, 0, stream>>>(Qn, Kn, probs);
    k_ao_scatter<<<8192, blk, 0, stream>>>(Vv, probs, attn);
    k_wo_ln    <<<2048, blk, 0, stream>>>(attn, Wo, bo, v, lng, lnb, hbuf);
    k_ffn      <<<2048, blk, 0, stream>>>(hbuf, W1, b1, W2, b2, lng, lnb, v, out);
}

// Round 2
// 473.673 us; speedup vs baseline: 2.3028x; 2.3028x over previous
//
#include <hip/hip_runtime.h>
#include <math.h>

// ============================================================================
// Cross-covariance transformer block.
// Round 2: FFN + Wo-projection moved to bf16 MFMA (post-median-mask => safe);
// QKV GEMMs + scores stay f32 (median mask is a hard threshold).
//
// Reshape semantics (raw row-major):
//   chunk p = tok/256 (512 chunks of 256 tokens); view-row (r=tok%256, j=chan/8)
//   Output perm: tok2 = g*8192 + r*32 + j*2 + b/16,  c2 = (b%16)*8 + d
//
// Pipeline:
//   k_gemm128 x3 : Qn, Kn (8-group L2-normalized), V          (f32)
//   k_scores     : 8x8 cross-cov + lower-median mask + softmax (f32)
//   k_wcvt       : W1/W2/Wo -> fragment-linear bf16
//   k_ao_scatter : AO = probs @ V-groups -> permuted attn (bf16)
//   k_wo_mfma    : h = LN(v + attn@Wo + bo)   [MFMA]  -> h (f32) + hbf (bf16)
//   k_ffn_mfma   : out = LN(h + gelu(h@W1+b1)@W2 + b2) + v   [MFMA]
// ============================================================================

typedef __bf16 bf16x8 __attribute__((ext_vector_type(8)));
typedef float f32x4 __attribute__((ext_vector_type(4)));
typedef unsigned short u16x8 __attribute__((ext_vector_type(8)));
typedef unsigned int u32x2 __attribute__((ext_vector_type(2)));

static constexpr int  DM   = 128;
static constexpr long NTOK = 131072;                 // B*S = 32*4096
static constexpr float NORMF = 0.17677669529663687f; // 1/sqrt(32)

__device__ __forceinline__ unsigned short f2b(float x) {
    unsigned u = __builtin_bit_cast(unsigned, x);
    return (unsigned short)((u + 0x7fffu + ((u >> 16) & 1u)) >> 16);  // RNE
}
__device__ __forceinline__ unsigned pack2(float a, float b) {
    return (unsigned)f2b(a) | ((unsigned)f2b(b) << 16);
}
__device__ __forceinline__ f32x4 mfma16(bf16x8 a, bf16x8 b, f32x4 c) {
    return __builtin_amdgcn_mfma_f32_16x16x32_bf16(a, b, c, 0, 0, 0);
}
// LDS swizzles: XOR low-3 chunk bits (16B chunks) with tok&7  (G4 / T2)
__device__ __forceinline__ int xb_off(int tok, int chunk) {   // [64][128] bf16
    int c = (chunk & 8) | ((chunk ^ tok) & 7);
    return tok * 128 + c * 8;
}
__device__ __forceinline__ int hid_off(int tok, int chunk) {  // [64][512] bf16
    int c = (chunk & ~7) | ((chunk ^ tok) & 7);
    return tok * 512 + c * 8;
}

// ---------------------------------------------------------------------------
// K1: out[t][c] = in[t]·W[:,c] + b[c]; optional L2-normalize per 8-chan group.
// ---------------------------------------------------------------------------
template<bool NORM>
__global__ __launch_bounds__(256)
void k_gemm128(const float* __restrict__ in, const float* __restrict__ W,
               const float* __restrict__ bias, float* __restrict__ out)
{
    __shared__ float Wl[128 * 132];
    __shared__ float xl[64 * 132];
    const int tid = threadIdx.x;
    const int gr  = tid & 15;
    const int ts  = tid >> 4;
    const long tok0 = (long)blockIdx.x * 64;

    const float4* W4 = (const float4*)W;
    #pragma unroll
    for (int i = 0; i < 16; ++i) {
        int e = tid + i * 256;
        int k = e >> 5, c4 = e & 31;
        float4 w = W4[e];
        float* dst = &Wl[k * 132 + c4 * 4];
        dst[0] = w.x; dst[1] = w.y; dst[2] = w.z; dst[3] = w.w;
    }
    const float4* in4 = (const float4*)(in + tok0 * DM);
    #pragma unroll
    for (int i = 0; i < 8; ++i) {
        int e = tid + i * 256;
        int t = e >> 5, c4 = e & 31;
        float4 xv = in4[e];
        float* dst = &xl[t * 132 + c4 * 4];
        dst[0] = xv.x; dst[1] = xv.y; dst[2] = xv.z; dst[3] = xv.w;
    }
    __syncthreads();

    float acc[4][8];
    #pragma unroll
    for (int m = 0; m < 4; ++m)
        #pragma unroll
        for (int i = 0; i < 8; ++i) acc[m][i] = 0.f;

    #pragma unroll 4
    for (int k = 0; k < 128; ++k) {
        const float4 wA = *(const float4*)&Wl[k * 132 + gr * 8];
        const float4 wB = *(const float4*)&Wl[k * 132 + gr * 8 + 4];
        #pragma unroll
        for (int m = 0; m < 4; ++m) {
            float xv = xl[(ts * 4 + m) * 132 + k];
            acc[m][0] = fmaf(xv, wA.x, acc[m][0]);
            acc[m][1] = fmaf(xv, wA.y, acc[m][1]);
            acc[m][2] = fmaf(xv, wA.z, acc[m][2]);
            acc[m][3] = fmaf(xv, wA.w, acc[m][3]);
            acc[m][4] = fmaf(xv, wB.x, acc[m][4]);
            acc[m][5] = fmaf(xv, wB.y, acc[m][5]);
            acc[m][6] = fmaf(xv, wB.z, acc[m][6]);
            acc[m][7] = fmaf(xv, wB.w, acc[m][7]);
        }
    }

    float bv[8];
    #pragma unroll
    for (int i = 0; i < 8; ++i) bv[i] = bias[gr * 8 + i];

    #pragma unroll
    for (int m = 0; m < 4; ++m) {
        float o[8];
        #pragma unroll
        for (int i = 0; i < 8; ++i) o[i] = acc[m][i] + bv[i];
        if (NORM) {
            float ss = 0.f;
            #pragma unroll
            for (int i = 0; i < 8; ++i) ss = fmaf(o[i], o[i], ss);
            float inv = 1.f / fmaxf(sqrtf(ss), 1e-12f);
            #pragma unroll
            for (int i = 0; i < 8; ++i) o[i] *= inv;
        }
        float* dst = out + (tok0 + ts * 4 + m) * DM + gr * 8;
        *(float4*)dst       = (float4){o[0], o[1], o[2], o[3]};
        *(float4*)(dst + 4) = (float4){o[4], o[5], o[6], o[7]};
    }
}

// ---------------------------------------------------------------------------
// K2: per chunk p: scores = QnT*Kn * NORMF; lower-median strict mask; softmax.
// ---------------------------------------------------------------------------
__global__ __launch_bounds__(256)
void k_scores(const float* __restrict__ Qn, const float* __restrict__ Kn,
              float* __restrict__ probs)
{
    __shared__ float red[256 * 65];
    __shared__ float part[4 * 64];
    __shared__ float sc[64];
    __shared__ float pl[64];
    const int tid = threadIdx.x;
    const long base = (long)blockIdx.x * 32768;

    float acc[64];
    #pragma unroll
    for (int i = 0; i < 64; ++i) acc[i] = 0.f;

    for (int it = 0; it < 16; ++it) {
        long pi = (long)it * 256 + tid;
        const float4* q4 = (const float4*)(Qn + base + pi * 8);
        const float4* k4 = (const float4*)(Kn + base + pi * 8);
        float4 qa = q4[0], qb = q4[1], ka = k4[0], kb = k4[1];
        float qv[8] = {qa.x, qa.y, qa.z, qa.w, qb.x, qb.y, qb.z, qb.w};
        float kv[8] = {ka.x, ka.y, ka.z, ka.w, kb.x, kb.y, kb.z, kb.w};
        #pragma unroll
        for (int d = 0; d < 8; ++d)
            #pragma unroll
            for (int e = 0; e < 8; ++e)
                acc[d * 8 + e] = fmaf(qv[d], kv[e], acc[d * 8 + e]);
    }

    #pragma unroll
    for (int i = 0; i < 64; ++i) red[tid * 65 + i] = acc[i];
    __syncthreads();

    {
        int g2 = tid >> 6, e = tid & 63;
        float s = 0.f;
        for (int t = 0; t < 64; ++t) s += red[(g2 * 64 + t) * 65 + e];
        part[g2 * 64 + e] = s;
    }
    __syncthreads();
    if (tid < 64)
        sc[tid] = (part[tid] + part[64 + tid] + part[128 + tid] + part[192 + tid]) * NORMF;
    __syncthreads();

    if (tid < 8) {
        float row[8], st[8];
        #pragma unroll
        for (int e = 0; e < 8; ++e) { row[e] = sc[tid * 8 + e]; st[e] = row[e]; }
        for (int a = 1; a < 8; ++a) {
            float v = st[a]; int b = a - 1;
            while (b >= 0 && st[b] > v) { st[b + 1] = st[b]; --b; }
            st[b + 1] = v;
        }
        float med = st[3];
        float mv[8]; float mx = -3.0e38f;
        #pragma unroll
        for (int e = 0; e < 8; ++e) {
            mv[e] = (row[e] - med > 0.f) ? row[e] : -1e30f;
            mx = fmaxf(mx, mv[e]);
        }
        float z = 0.f, ex[8];
        #pragma unroll
        for (int e = 0; e < 8; ++e) { ex[e] = expf(mv[e] - mx); z += ex[e]; }
        float iz = 1.f / z;
        #pragma unroll
        for (int e = 0; e < 8; ++e) pl[tid * 8 + e] = ex[e] * iz;
    }
    __syncthreads();
    if (tid < 64) probs[(long)blockIdx.x * 64 + tid] = pl[tid];
}

// ---------------------------------------------------------------------------
// k_wcvt: gather W1/W2/Wo into MFMA-A-fragment-linear bf16 arrays.
// A-frag (m,k): value = W[k][m]; lane l: m = frag_m*16 + (l&15),
// k = frag_k*32 + (l>>4)*8 + j.  Flat: Wt[(frag*64 + l)*8 + j].
// ---------------------------------------------------------------------------
__global__ __launch_bounds__(256)
void k_wcvt(const float* __restrict__ W1, const float* __restrict__ W2,
            const float* __restrict__ Wo, unsigned short* __restrict__ W1t,
            unsigned short* __restrict__ W2t, unsigned short* __restrict__ Wot)
{
    int frag = blockIdx.x * 4 + (threadIdx.x >> 6);
    int l = threadIdx.x & 63;
    int lr = l & 15, lg = l >> 4;
    u16x8 v;
    if (frag < 128) {                       // W1t: 32 hcol-tiles x 4 k-steps
        int ht = frag >> 2, ks = frag & 3;
        #pragma unroll
        for (int j = 0; j < 8; ++j)
            v[j] = f2b(W1[(ks * 32 + lg * 8 + j) * 512 + ht * 16 + lr]);
        *(u16x8*)(W1t + ((long)frag * 64 + l) * 8) = v;
    } else if (frag < 256) {                // W2t: 8 oc-tiles x 16 k-steps
        int f = frag - 128;
        int ot = f >> 4, ks = f & 15;
        #pragma unroll
        for (int j = 0; j < 8; ++j)
            v[j] = f2b(W2[(ks * 32 + lg * 8 + j) * 128 + ot * 16 + lr]);
        *(u16x8*)(W2t + ((long)f * 64 + l) * 8) = v;
    } else {                                // Wot: 8 oc-tiles x 4 k-steps
        int f = frag - 256;
        int ot = f >> 2, ks = f & 3;
        #pragma unroll
        for (int j = 0; j < 8; ++j)
            v[j] = f2b(Wo[(ks * 32 + lg * 8 + j) * 128 + ot * 16 + lr]);
        *(u16x8*)(Wot + ((long)f * 64 + l) * 8) = v;
    }
}

// ---------------------------------------------------------------------------
// K3: AO + scatter into permuted attn matrix (bf16 output).
// ---------------------------------------------------------------------------
__global__ __launch_bounds__(256)
void k_ao_scatter(const float* __restrict__ V, const float* __restrict__ probs,
                  unsigned short* __restrict__ attnbf)
{
    __shared__ float pl[64];
    const int tid = threadIdx.x;
    const int p = blockIdx.x >> 4;
    if (tid < 64) pl[tid] = probs[(long)p * 64 + tid];
    __syncthreads();

    const long w = (long)blockIdx.x * 256 + tid;
    const long t = w >> 4;
    const int  j = (int)(w & 15);
    const int  r = (int)(t & 255);
    const int  g = p >> 5, b = p & 31;

    const float4* v4 = (const float4*)(V + t * DM + j * 8);
    float4 va = v4[0], vb = v4[1];
    float vv[8] = {va.x, va.y, va.z, va.w, vb.x, vb.y, vb.z, vb.w};
    u16x8 pkt;
    #pragma unroll
    for (int d = 0; d < 8; ++d) {
        float s = 0.f;
        #pragma unroll
        for (int e = 0; e < 8; ++e) s = fmaf(pl[d * 8 + e], vv[e], s);
        pkt[d] = f2b(s);
    }
    const long tok2 = (long)g * 8192 + r * 32 + j * 2 + (b >> 4);
    *(u16x8*)(attnbf + tok2 * DM + (b & 15) * 8) = pkt;
}

// ---------------------------------------------------------------------------
// k_wo_mfma: h = LN(v + attn@Wo + bo)  -> h (f32) and hbf (bf16)
// 64 tok/block, 4 waves; wave owns 32 output cols.  MFMA D[row=oc][col=tok].
// ---------------------------------------------------------------------------
__global__ __launch_bounds__(256)
void k_wo_mfma(const unsigned short* __restrict__ attnbf,
               const unsigned short* __restrict__ Wot,
               const float* __restrict__ bo,
               const float* __restrict__ vres,
               const float* __restrict__ lng, const float* __restrict__ lnb,
               float* __restrict__ h, unsigned short* __restrict__ hbf)
{
    __shared__ __align__(16) unsigned short Xb[64 * 128];
    __shared__ float pS[256], pQ[256], muS[64], rsS[64];
    const int tid = threadIdx.x;
    const int w = tid >> 6, l = tid & 63;
    const int lr = l & 15, lg = l >> 4;
    const long tok0 = (long)blockIdx.x * 64;

    #pragma unroll
    for (int i = 0; i < 4; ++i) {
        int e = tid + i * 256;
        int tok = e >> 4, c = e & 15;
        u16x8 val = *(const u16x8*)(attnbf + (tok0 + tok) * DM + c * 8);
        *(u16x8*)(Xb + xb_off(tok, c)) = val;
    }

    bf16x8 aw[2][4];
    #pragma unroll
    for (int ot = 0; ot < 2; ++ot)
        #pragma unroll
        for (int ks = 0; ks < 4; ++ks)
            aw[ot][ks] = *(const bf16x8*)(Wot + ((long)((w * 2 + ot) * 4 + ks) * 64 + l) * 8);

    f32x4 bov[2], g4[2], bb4[2];
    #pragma unroll
    for (int ot = 0; ot < 2; ++ot) {
        int oc0 = w * 32 + ot * 16 + lg * 4;
        bov[ot] = *(const f32x4*)(bo + oc0);
        g4[ot]  = *(const f32x4*)(lng + oc0);
        bb4[ot] = *(const f32x4*)(lnb + oc0);
    }
    __syncthreads();

    float vals[4][2][4];
    float sums[4], sqs[4];
    #pragma unroll
    for (int tt = 0; tt < 4; ++tt) {
        f32x4 acc[2] = {(f32x4){0,0,0,0}, (f32x4){0,0,0,0}};
        int tok = tt * 16 + lr;
        #pragma unroll
        for (int ks = 0; ks < 4; ++ks) {
            bf16x8 bfrag = *(const bf16x8*)(Xb + xb_off(tok, ks * 4 + lg));
            acc[0] = mfma16(aw[0][ks], bfrag, acc[0]);
            acc[1] = mfma16(aw[1][ks], bfrag, acc[1]);
        }
        long gtok = tok0 + tok;
        float s = 0.f, q = 0.f;
        #pragma unroll
        for (int ot = 0; ot < 2; ++ot) {
            int oc0 = w * 32 + ot * 16 + lg * 4;
            f32x4 xv = *(const f32x4*)(vres + gtok * DM + oc0);
            #pragma unroll
            for (int r = 0; r < 4; ++r) {
                float vv = acc[ot][r] + bov[ot][r] + xv[r];
                vals[tt][ot][r] = vv;
                s += vv; q = fmaf(vv, vv, q);
            }
        }
        sums[tt] = s; sqs[tt] = q;
    }
    #pragma unroll
    for (int tt = 0; tt < 4; ++tt) {
        sums[tt] += __shfl_xor(sums[tt], 16, 64);
        sums[tt] += __shfl_xor(sums[tt], 32, 64);
        sqs[tt]  += __shfl_xor(sqs[tt], 16, 64);
        sqs[tt]  += __shfl_xor(sqs[tt], 32, 64);
    }
    #pragma unroll
    for (int tt = 0; tt < 4; ++tt)
        if (lg == tt) { pS[(w * 4 + tt) * 16 + lr] = sums[tt];
                        pQ[(w * 4 + tt) * 16 + lr] = sqs[tt]; }
    __syncthreads();
    if (tid < 64) {
        float s = pS[tid] + pS[64 + tid] + pS[128 + tid] + pS[192 + tid];
        float q = pQ[tid] + pQ[64 + tid] + pQ[128 + tid] + pQ[192 + tid];
        float mu = s * 0.0078125f;
        float var = q * 0.0078125f - mu * mu;
        muS[tid] = mu;
        rsS[tid] = rsqrtf(var + 1e-5f);
    }
    __syncthreads();
    #pragma unroll
    for (int tt = 0; tt < 4; ++tt) {
        int tokl = tt * 16 + lr;
        long gtok = tok0 + tokl;
        float mu = muS[tokl], rs = rsS[tokl];
        #pragma unroll
        for (int ot = 0; ot < 2; ++ot) {
            int oc0 = w * 32 + ot * 16 + lg * 4;
            f32x4 o;
            #pragma unroll
            for (int r = 0; r < 4; ++r)
                o[r] = (vals[tt][ot][r] - mu) * rs * g4[ot][r] + bb4[ot][r];
            *(f32x4*)(h + gtok * DM + oc0) = o;
            u32x2 pk = {pack2(o[0], o[1]), pack2(o[2], o[3])};
            *(u32x2*)(hbf + gtok * DM + oc0) = pk;
        }
    }
}

// ---------------------------------------------------------------------------
// k_ffn_mfma: out = LN(h + gelu(h@W1+b1)@W2 + b2) + v   [MFMA, bf16]
// 64 tok/block, 4 waves. Stage1: wave owns 128 hidden cols, D[hcol][tok]
// -> ds_write_b64 of 4 packed bf16. Stage2: wave owns 32 out cols.
// ---------------------------------------------------------------------------
__global__ __launch_bounds__(256, 2)
void k_ffn_mfma(const unsigned short* __restrict__ hbf,
                const float* __restrict__ hres,
                const unsigned short* __restrict__ W1t,
                const float* __restrict__ b1,
                const unsigned short* __restrict__ W2t,
                const float* __restrict__ b2,
                const float* __restrict__ lng, const float* __restrict__ lnb,
                const float* __restrict__ vres, float* __restrict__ out)
{
    __shared__ __align__(16) char smem[81920];
    unsigned short* Xb  = (unsigned short*)smem;            // 16 KB
    unsigned short* Hid = (unsigned short*)(smem + 16384);  // 64 KB
    float* pS  = (float*)smem;                              // alias Xb (dead)
    float* pQ  = pS + 256;
    float* muS = pQ + 256;
    float* rsS = muS + 64;

    const int tid = threadIdx.x;
    const int w = tid >> 6, l = tid & 63;
    const int lr = l & 15, lg = l >> 4;
    const long tok0 = (long)blockIdx.x * 64;

    // stage X (bf16 h) into LDS
    #pragma unroll
    for (int i = 0; i < 4; ++i) {
        int e = tid + i * 256;
        int tok = e >> 4, c = e & 15;
        u16x8 val = *(const u16x8*)(hbf + (tok0 + tok) * DM + c * 8);
        *(u16x8*)(Xb + xb_off(tok, c)) = val;
    }

    bf16x8 a1[8][4];
    #pragma unroll
    for (int ht = 0; ht < 8; ++ht)
        #pragma unroll
        for (int ks = 0; ks < 4; ++ks)
            a1[ht][ks] = *(const bf16x8*)(W1t + ((long)((w * 8 + ht) * 4 + ks) * 64 + l) * 8);
    f32x4 b1v[8];
    #pragma unroll
    for (int ht = 0; ht < 8; ++ht)
        b1v[ht] = *(const f32x4*)(b1 + w * 128 + ht * 16 + lg * 4);

    __syncthreads();

    // ---- stage 1: Hid = gelu(X@W1 + b1), transposed D ----
    #pragma unroll
    for (int tt = 0; tt < 4; ++tt) {
        f32x4 acc[8];
        #pragma unroll
        for (int ht = 0; ht < 8; ++ht) acc[ht] = (f32x4){0, 0, 0, 0};
        int tok = tt * 16 + lr;
        #pragma unroll
        for (int ks = 0; ks < 4; ++ks) {
            bf16x8 bfrag = *(const bf16x8*)(Xb + xb_off(tok, ks * 4 + lg));
            #pragma unroll
            for (int ht = 0; ht < 8; ++ht)
                acc[ht] = mfma16(a1[ht][ks], bfrag, acc[ht]);
        }
        #pragma unroll
        for (int ht = 0; ht < 8; ++ht) {
            float g[4];
            #pragma unroll
            for (int r = 0; r < 4; ++r) {
                float x = acc[ht][r] + b1v[ht][r];
                g[r] = 0.5f * x * (1.f + erff(x * 0.70710678118654752f));
            }
            int hc0 = w * 128 + ht * 16 + lg * 4;
            int elem = hid_off(tok, hc0 >> 3) + (hc0 & 7);
            u32x2 pk = {pack2(g[0], g[1]), pack2(g[2], g[3])};
            *(u32x2*)(Hid + elem) = pk;
        }
    }
    __syncthreads();
    __builtin_amdgcn_sched_barrier(0);   // keep a2 loads out of stage 1

    bf16x8 a2[2][16];
    #pragma unroll
    for (int ot = 0; ot < 2; ++ot)
        #pragma unroll
        for (int ks = 0; ks < 16; ++ks)
            a2[ot][ks] = *(const bf16x8*)(W2t + ((long)((w * 2 + ot) * 16 + ks) * 64 + l) * 8);

    f32x4 b2v[2], g4[2], bb4[2];
    #pragma unroll
    for (int ot = 0; ot < 2; ++ot) {
        int oc0 = w * 32 + ot * 16 + lg * 4;
        b2v[ot] = *(const f32x4*)(b2 + oc0);
        g4[ot]  = *(const f32x4*)(lng + oc0);
        bb4[ot] = *(const f32x4*)(lnb + oc0);
    }

    // ---- stage 2: out cols [w*32, w*32+32) ----
    float vals[4][2][4];
    float sums[4], sqs[4];
    #pragma unroll
    for (int tt = 0; tt < 4; ++tt) {
        f32x4 acc[2] = {(f32x4){0,0,0,0}, (f32x4){0,0,0,0}};
        int tok = tt * 16 + lr;
        #pragma unroll
        for (int ks = 0; ks < 16; ++ks) {
            bf16x8 bfrag = *(const bf16x8*)(Hid + hid_off(tok, ks * 4 + lg));
            acc[0] = mfma16(a2[0][ks], bfrag, acc[0]);
            acc[1] = mfma16(a2[1][ks], bfrag, acc[1]);
        }
        long gtok = tok0 + tok;
        float s = 0.f, q = 0.f;
        #pragma unroll
        for (int ot = 0; ot < 2; ++ot) {
            int oc0 = w * 32 + ot * 16 + lg * 4;
            f32x4 xr = *(const f32x4*)(hres + gtok * DM + oc0);
            #pragma unroll
            for (int r = 0; r < 4; ++r) {
                float vv = acc[ot][r] + b2v[ot][r] + xr[r];
                vals[tt][ot][r] = vv;
                s += vv; q = fmaf(vv, vv, q);
            }
        }
        sums[tt] = s; sqs[tt] = q;
    }
    #pragma unroll
    for (int tt = 0; tt < 4; ++tt) {
        sums[tt] += __shfl_xor(sums[tt], 16, 64);
        sums[tt] += __shfl_xor(sums[tt], 32, 64);
        sqs[tt]  += __shfl_xor(sqs[tt], 16, 64);
        sqs[tt]  += __shfl_xor(sqs[tt], 32, 64);
    }
    #pragma unroll
    for (int tt = 0; tt < 4; ++tt)
        if (lg == tt) { pS[(w * 4 + tt) * 16 + lr] = sums[tt];
                        pQ[(w * 4 + tt) * 16 + lr] = sqs[tt]; }
    __syncthreads();
    if (tid < 64) {
        float s = pS[tid] + pS[64 + tid] + pS[128 + tid] + pS[192 + tid];
        float q = pQ[tid] + pQ[64 + tid] + pQ[128 + tid] + pQ[192 + tid];
        float mu = s * 0.0078125f;
        float var = q * 0.0078125f - mu * mu;
        muS[tid] = mu;
        rsS[tid] = rsqrtf(var + 1e-5f);
    }
    __syncthreads();
    #pragma unroll
    for (int tt = 0; tt < 4; ++tt) {
        int tokl = tt * 16 + lr;
        long gtok = tok0 + tokl;
        float mu = muS[tokl], rs = rsS[tokl];
        #pragma unroll
        for (int ot = 0; ot < 2; ++ot) {
            int oc0 = w * 32 + ot * 16 + lg * 4;
            f32x4 vv = *(const f32x4*)(vres + gtok * DM + oc0);
            f32x4 o;
            #pragma unroll
            for (int r = 0; r < 4; ++r)
                o[r] = (vals[tt][ot][r] - mu) * rs * g4[ot][r] + bb4[ot][r] + vv[r];
            *(f32x4*)(out + gtok * DM + oc0) = o;
        }
    }
}

// ---------------------------------------------------------------------------
extern "C" void kernel_launch(void* const* d_in, const int* in_sizes, int n_in,
                              void* d_out, int out_size, void* d_ws, size_t ws_size,
                              hipStream_t stream)
{
    const float* q   = (const float*)d_in[0];
    const float* v   = (const float*)d_in[1];
    const float* Wq  = (const float*)d_in[2];
    const float* bq  = (const float*)d_in[3];
    const float* Wk  = (const float*)d_in[4];
    const float* bk  = (const float*)d_in[5];
    const float* Wv  = (const float*)d_in[6];
    const float* bv  = (const float*)d_in[7];
    const float* Wo  = (const float*)d_in[8];
    const float* bo  = (const float*)d_in[9];
    const float* lng = (const float*)d_in[10];
    const float* lnb = (const float*)d_in[11];
    const float* W1  = (const float*)d_in[12];
    const float* b1  = (const float*)d_in[13];
    const float* W2  = (const float*)d_in[14];
    const float* b2  = (const float*)d_in[15];
    float* out = (float*)d_out;

    // Region A [0,64MB): Qn f32 -> (after k_scores) W1t/W2t/Wot bf16
    // Region B [64,128MB): Kn f32 -> attnbf (32MB) + hbf (32MB)
    // Region C [128,192MB): Vv f32 -> h f32
    // Region D [192MB,+128KB): probs f32
    float* Qn    = (float*)d_ws;
    float* Kn    = Qn + NTOK * DM;
    float* Vv    = Kn + NTOK * DM;
    float* probs = Vv + NTOK * DM;
    unsigned short* W1t    = (unsigned short*)d_ws;        // 64K elems
    unsigned short* W2t    = W1t + 65536;                  // 64K elems
    unsigned short* Wot    = W2t + 65536;                  // 16K elems
    unsigned short* attnbf = (unsigned short*)d_ws + 33554432;  // byte 64MB
    unsigned short* hbf    = attnbf + NTOK * DM;                // byte 96MB
    float* hres = Vv;                                            // reuse C

    dim3 blk(256);
    k_gemm128<true ><<<2048, blk, 0, stream>>>(v, Wq, bq, Qn);
    k_gemm128<true ><<<2048, blk, 0, stream>>>(q, Wk, bk, Kn);
    k_gemm128<false><<<2048, blk, 0, stream>>>(q, Wv, bv, Vv);
    k_scores<<<512, blk, 0, stream>>>(Qn, Kn, probs);
    k_wcvt<<<72, blk, 0, stream>>>(W1, W2, Wo, W1t, W2t, Wot);
    k_ao_scatter<<<8192, blk, 0, stream>>>(Vv, probs, attnbf);
    k_wo_mfma<<<2048, blk, 0, stream>>>(attnbf, Wot, bo, v, lng, lnb, hres, hbf);
    k_ffn_mfma<<<2048, blk, 0, stream>>>(hbf, hres, W1t, b1, W2t, b2, lng, lnb, v, out);
}

// Round 3
// 254.517 us; speedup vs baseline: 4.2857x; 1.8611x over previous
//
#include <hip/hip_runtime.h>
#include <math.h>

// ============================================================================
// Cross-covariance transformer block.  Round 3:
//  - k_qkvs: fused QKV projection (split-bf16 MFMA, ~f32 accurate) +
//    8-group L2 norm + per-block partial 8x8 score reduction (deterministic,
//    no atomics).  Qn/Kn never hit global memory; V stored bf16.
//  - k_medsoft: per-chunk median mask + softmax (512 x 64).
//  - k_ffn_mfma: fast erf (A&S 7.1.26), hidden sliced 2x256 -> 51 KB LDS,
//    3 blocks/CU.
// Reshape semantics: chunk p = tok/256; view-row (r=tok%256, j=chan/8);
// output perm tok2 = g*8192+r*32+j*2+b/16, c2 = (b%16)*8+d.
// ============================================================================

typedef __bf16 bf16x8 __attribute__((ext_vector_type(8)));
typedef float f32x4 __attribute__((ext_vector_type(4)));
typedef unsigned short u16x8 __attribute__((ext_vector_type(8)));
typedef unsigned int u32x2 __attribute__((ext_vector_type(2)));
typedef unsigned short ushort_t;

static constexpr int  DM   = 128;
static constexpr long NTOK = 131072;                 // B*S = 32*4096
static constexpr float NORMF = 0.17677669529663687f; // 1/sqrt(32)

__device__ __forceinline__ unsigned short f2b(float x) {
    unsigned u = __builtin_bit_cast(unsigned, x);
    return (unsigned short)((u + 0x7fffu + ((u >> 16) & 1u)) >> 16);  // RNE
}
__device__ __forceinline__ float b2f(unsigned short h) {
    return __builtin_bit_cast(float, ((unsigned)h) << 16);
}
__device__ __forceinline__ unsigned pack2(float a, float b) {
    return (unsigned)f2b(a) | ((unsigned)f2b(b) << 16);
}
__device__ __forceinline__ f32x4 mfma16(bf16x8 a, bf16x8 b, f32x4 c) {
    return __builtin_amdgcn_mfma_f32_16x16x32_bf16(a, b, c, 0, 0, 0);
}
// [64][128] bf16 tile, 16B chunks XOR-swizzled by tok&7
__device__ __forceinline__ int xb_off(int tok, int chunk) {
    int c = (chunk & 8) | ((chunk ^ tok) & 7);
    return tok * 128 + c * 8;
}
// [64][256] bf16 tile
__device__ __forceinline__ int h2_off(int tok, int chunk) {
    int c = (chunk & 24) | ((chunk ^ tok) & 7);
    return tok * 256 + c * 8;
}
// gelu via A&S 7.1.26 erf approx (|err| ~1.5e-7)
__device__ __forceinline__ float gelu_f(float x) {
    float t = 0.70710678118654752f * x;
    float s = fabsf(t);
    float u = __builtin_amdgcn_rcpf(fmaf(0.3275911f, s, 1.0f));
    float p = fmaf(fmaf(fmaf(fmaf(1.061405429f, u, -1.453152027f), u,
                             1.421413741f), u, -0.284496736f), u, 0.254829592f);
    p *= u;
    float e = __expf(-s * s);
    float er = fmaf(-p, e, 1.0f);
    er = (t < 0.f) ? -er : er;
    return 0.5f * x * (1.0f + er);
}

// ---------------------------------------------------------------------------
// k_wcvt: weights -> MFMA-A-fragment-linear bf16 (W1/W2/Wo single, Wq/Wk/Wv
// hi/lo split).  A-frag: value = W[k][m], m = ot*16+lr, k = ks*32+lg*8+j.
// ---------------------------------------------------------------------------
__global__ __launch_bounds__(256)
void k_wcvt(const float* __restrict__ W1, const float* __restrict__ W2,
            const float* __restrict__ Wo, const float* __restrict__ Wq,
            const float* __restrict__ Wk, const float* __restrict__ Wv,
            ushort_t* __restrict__ W1t, ushort_t* __restrict__ W2t,
            ushort_t* __restrict__ Wot,
            ushort_t* __restrict__ Wqh, ushort_t* __restrict__ Wql,
            ushort_t* __restrict__ Wkh, ushort_t* __restrict__ Wkl,
            ushort_t* __restrict__ Wvh, ushort_t* __restrict__ Wvl)
{
    int frag = blockIdx.x * 4 + (threadIdx.x >> 6);
    int l = threadIdx.x & 63;
    int lr = l & 15, lg = l >> 4;
    u16x8 v;
    if (frag < 128) {                       // W1t: 32 hcol-tiles x 4 k-steps
        int ht = frag >> 2, ks = frag & 3;
        #pragma unroll
        for (int j = 0; j < 8; ++j)
            v[j] = f2b(W1[(ks * 32 + lg * 8 + j) * 512 + ht * 16 + lr]);
        *(u16x8*)(W1t + ((long)frag * 64 + l) * 8) = v;
    } else if (frag < 256) {                // W2t: 8 oc-tiles x 16 k-steps
        int f = frag - 128;
        int ot = f >> 4, ks = f & 15;
        #pragma unroll
        for (int j = 0; j < 8; ++j)
            v[j] = f2b(W2[(ks * 32 + lg * 8 + j) * 128 + ot * 16 + lr]);
        *(u16x8*)(W2t + ((long)f * 64 + l) * 8) = v;
    } else if (frag < 288) {                // Wot: 8 oc-tiles x 4 k-steps
        int f = frag - 256;
        int ot = f >> 2, ks = f & 3;
        #pragma unroll
        for (int j = 0; j < 8; ++j)
            v[j] = f2b(Wo[(ks * 32 + lg * 8 + j) * 128 + ot * 16 + lr]);
        *(u16x8*)(Wot + ((long)f * 64 + l) * 8) = v;
    } else {                                // Wq/Wk/Wv hi+lo, 32 frags each
        int f = frag - 288;
        const float* S = (f < 32) ? Wq : (f < 64) ? Wk : Wv;
        ushort_t* dh = (f < 32) ? Wqh : (f < 64) ? Wkh : Wvh;
        ushort_t* dl = (f < 32) ? Wql : (f < 64) ? Wkl : Wvl;
        int fl = f & 31, ot = fl >> 2, ks = fl & 3;
        u16x8 vh, vl;
        #pragma unroll
        for (int j = 0; j < 8; ++j) {
            float x = S[(ks * 32 + lg * 8 + j) * 128 + ot * 16 + lr];
            unsigned short h = f2b(x);
            vh[j] = h;
            vl[j] = f2b(x - b2f(h));
        }
        *(u16x8*)(dh + ((long)fl * 64 + l) * 8) = vh;
        *(u16x8*)(dl + ((long)fl * 64 + l) * 8) = vl;
    }
}

// ---------------------------------------------------------------------------
// k_qkvs: 64 tokens/block.  Split-bf16 MFMA for Q (from v), K,V (from q);
// 8-group normalize Q,K; partial scores -> scoreacc[block][64];
// V (bf16) -> global via LDS transpose.
// ---------------------------------------------------------------------------
__global__ __launch_bounds__(256, 2)
void k_qkvs(const float* __restrict__ qin, const float* __restrict__ vin,
            const ushort_t* __restrict__ Wqh, const ushort_t* __restrict__ Wql,
            const ushort_t* __restrict__ Wkh, const ushort_t* __restrict__ Wkl,
            const ushort_t* __restrict__ Wvh, const ushort_t* __restrict__ Wvl,
            const float* __restrict__ bq, const float* __restrict__ bk,
            const float* __restrict__ bv,
            ushort_t* __restrict__ Vbf, float* __restrict__ scoreacc)
{
    __shared__ __align__(16) char smem[65536];
    ushort_t* vhi = (ushort_t*)smem;            // [64][128] swz  (input v)
    ushort_t* vlo = vhi + 8192;
    ushort_t* qhi = vlo + 8192;                 // (input q)
    ushort_t* qlo = qhi + 8192;
    ushort_t* Vt  = (ushort_t*)smem;            // alias (16 KB) after phases
    float*    red = (float*)(smem + 16384);     // [16][33] alias

    const int tid = threadIdx.x;
    const int w = tid >> 6, l = tid & 63;
    const int lr = l & 15, lg = l >> 4;
    const long tok0 = (long)blockIdx.x * 64;

    // ---- stage inputs, split hi/lo ----
    #pragma unroll
    for (int i = 0; i < 4; ++i) {
        int e = tid + i * 256;
        int tok = e >> 4, c = e & 15;
        long base = (tok0 + tok) * DM + c * 8;
        int xo = xb_off(tok, c);
        {
            float4 a0 = *(const float4*)(vin + base);
            float4 a1 = *(const float4*)(vin + base + 4);
            float xs[8] = {a0.x, a0.y, a0.z, a0.w, a1.x, a1.y, a1.z, a1.w};
            u16x8 hi, lo;
            #pragma unroll
            for (int jj = 0; jj < 8; ++jj) {
                unsigned short h = f2b(xs[jj]);
                hi[jj] = h; lo[jj] = f2b(xs[jj] - b2f(h));
            }
            *(u16x8*)(vhi + xo) = hi;
            *(u16x8*)(vlo + xo) = lo;
        }
        {
            float4 a0 = *(const float4*)(qin + base);
            float4 a1 = *(const float4*)(qin + base + 4);
            float xs[8] = {a0.x, a0.y, a0.z, a0.w, a1.x, a1.y, a1.z, a1.w};
            u16x8 hi, lo;
            #pragma unroll
            for (int jj = 0; jj < 8; ++jj) {
                unsigned short h = f2b(xs[jj]);
                hi[jj] = h; lo[jj] = f2b(xs[jj] - b2f(h));
            }
            *(u16x8*)(qhi + xo) = hi;
            *(u16x8*)(qlo + xo) = lo;
        }
    }
    __syncthreads();

    // ---- Q phase (input v) ----
    float qv[2][4][4];
    {
        f32x4 acc[2][4];
        #pragma unroll
        for (int ot = 0; ot < 2; ++ot)
            #pragma unroll
            for (int tt = 0; tt < 4; ++tt) acc[ot][tt] = (f32x4){0,0,0,0};
        #pragma unroll
        for (int ks = 0; ks < 4; ++ks) {
            bf16x8 wh[2], wl[2];
            #pragma unroll
            for (int ot = 0; ot < 2; ++ot) {
                int fi = (((w * 2 + ot) * 4 + ks) * 64 + l) * 8;
                wh[ot] = *(const bf16x8*)(Wqh + fi);
                wl[ot] = *(const bf16x8*)(Wql + fi);
            }
            #pragma unroll
            for (int tt = 0; tt < 4; ++tt) {
                int xo = xb_off(tt * 16 + lr, ks * 4 + lg);
                bf16x8 xh = *(const bf16x8*)(vhi + xo);
                bf16x8 xl = *(const bf16x8*)(vlo + xo);
                #pragma unroll
                for (int ot = 0; ot < 2; ++ot) {
                    acc[ot][tt] = mfma16(wh[ot], xh, acc[ot][tt]);
                    acc[ot][tt] = mfma16(wh[ot], xl, acc[ot][tt]);
                    acc[ot][tt] = mfma16(wl[ot], xh, acc[ot][tt]);
                }
            }
        }
        #pragma unroll
        for (int ot = 0; ot < 2; ++ot) {
            f32x4 bqv = *(const f32x4*)(bq + w * 32 + ot * 16 + lg * 4);
            #pragma unroll
            for (int tt = 0; tt < 4; ++tt) {
                float s2 = 0.f;
                #pragma unroll
                for (int r = 0; r < 4; ++r) {
                    float x = acc[ot][tt][r] + bqv[r];
                    qv[ot][tt][r] = x;
                    s2 = fmaf(x, x, s2);
                }
                s2 += __shfl_xor(s2, 16);
                float inv = 1.0f / fmaxf(sqrtf(s2), 1e-12f);
                #pragma unroll
                for (int r = 0; r < 4; ++r) qv[ot][tt][r] *= inv;
            }
        }
    }

    // ---- K+V phase (input q) + incremental score accumulation ----
    float vv[2][4][4];
    float part[4][8];
    #pragma unroll
    for (int r = 0; r < 4; ++r)
        #pragma unroll
        for (int e = 0; e < 8; ++e) part[r][e] = 0.f;
    {
        f32x4 acck[2][4], accv[2][4];
        #pragma unroll
        for (int ot = 0; ot < 2; ++ot)
            #pragma unroll
            for (int tt = 0; tt < 4; ++tt) {
                acck[ot][tt] = (f32x4){0,0,0,0};
                accv[ot][tt] = (f32x4){0,0,0,0};
            }
        #pragma unroll
        for (int ks = 0; ks < 4; ++ks) {
            bf16x8 whk[2], wlk[2], whv[2], wlv[2];
            #pragma unroll
            for (int ot = 0; ot < 2; ++ot) {
                int fi = (((w * 2 + ot) * 4 + ks) * 64 + l) * 8;
                whk[ot] = *(const bf16x8*)(Wkh + fi);
                wlk[ot] = *(const bf16x8*)(Wkl + fi);
                whv[ot] = *(const bf16x8*)(Wvh + fi);
                wlv[ot] = *(const bf16x8*)(Wvl + fi);
            }
            #pragma unroll
            for (int tt = 0; tt < 4; ++tt) {
                int xo = xb_off(tt * 16 + lr, ks * 4 + lg);
                bf16x8 xh = *(const bf16x8*)(qhi + xo);
                bf16x8 xl = *(const bf16x8*)(qlo + xo);
                #pragma unroll
                for (int ot = 0; ot < 2; ++ot) {
                    acck[ot][tt] = mfma16(whk[ot], xh, acck[ot][tt]);
                    acck[ot][tt] = mfma16(whk[ot], xl, acck[ot][tt]);
                    acck[ot][tt] = mfma16(wlk[ot], xh, acck[ot][tt]);
                    accv[ot][tt] = mfma16(whv[ot], xh, accv[ot][tt]);
                    accv[ot][tt] = mfma16(whv[ot], xl, accv[ot][tt]);
                    accv[ot][tt] = mfma16(wlv[ot], xh, accv[ot][tt]);
                }
            }
        }
        const int h0 = (lg & 1) * 4;
        #pragma unroll
        for (int ot = 0; ot < 2; ++ot) {
            f32x4 bkv = *(const f32x4*)(bk + w * 32 + ot * 16 + lg * 4);
            f32x4 bvv = *(const f32x4*)(bv + w * 32 + ot * 16 + lg * 4);
            #pragma unroll
            for (int tt = 0; tt < 4; ++tt) {
                float kq[4];
                float s2 = 0.f;
                #pragma unroll
                for (int r = 0; r < 4; ++r) {
                    float x = acck[ot][tt][r] + bkv[r];
                    kq[r] = x;
                    s2 = fmaf(x, x, s2);
                    vv[ot][tt][r] = accv[ot][tt][r] + bvv[r];
                }
                s2 += __shfl_xor(s2, 16);
                float inv = 1.0f / fmaxf(sqrtf(s2), 1e-12f);
                #pragma unroll
                for (int r = 0; r < 4; ++r) kq[r] *= inv;
                float ko[4];
                #pragma unroll
                for (int r = 0; r < 4; ++r) ko[r] = __shfl_xor(kq[r], 16);
                float ke[8];
                #pragma unroll
                for (int r = 0; r < 4; ++r) {
                    ke[h0 + r] = kq[r];
                    ke[(h0 ^ 4) + r] = ko[r];
                }
                #pragma unroll
                for (int r = 0; r < 4; ++r)
                    #pragma unroll
                    for (int e = 0; e < 8; ++e)
                        part[r][e] = fmaf(qv[ot][tt][r], ke[e], part[r][e]);
            }
        }
    }
    // reduce partials over lr lanes (bits 0..3)
    #pragma unroll
    for (int r = 0; r < 4; ++r)
        #pragma unroll
        for (int e = 0; e < 8; ++e) {
            float p = part[r][e];
            p += __shfl_xor(p, 1);
            p += __shfl_xor(p, 2);
            p += __shfl_xor(p, 4);
            p += __shfl_xor(p, 8);
            part[r][e] = p;
        }
    __syncthreads();   // x-tiles fully consumed; alias regions now writable

    // V regs -> Vt (swizzled bf16 [64][128])
    #pragma unroll
    for (int ot = 0; ot < 2; ++ot) {
        int oc0 = w * 32 + ot * 16 + lg * 4;
        int ch = oc0 >> 3;
        #pragma unroll
        for (int tt = 0; tt < 4; ++tt) {
            int tok = tt * 16 + lr;
            int cz = (ch & 8) | ((ch ^ tok) & 7);
            u32x2 pk = {pack2(vv[ot][tt][0], vv[ot][tt][1]),
                        pack2(vv[ot][tt][2], vv[ot][tt][3])};
            *(u32x2*)(Vt + tok * 128 + cz * 8 + (oc0 & 7)) = pk;
        }
    }
    if (lr == 0) {
        #pragma unroll
        for (int r = 0; r < 4; ++r)
            #pragma unroll
            for (int e = 0; e < 8; ++e)
                red[(w * 4 + lg) * 33 + r * 8 + e] = part[r][e];
    }
    __syncthreads();

    // coalesced V store
    #pragma unroll
    for (int i = 0; i < 4; ++i) {
        int e = tid + i * 256;
        int tok = e >> 4, c = e & 15;
        int cz = (c & 8) | ((c ^ tok) & 7);
        u16x8 val = *(const u16x8*)(Vt + tok * 128 + cz * 8);
        *(u16x8*)(Vbf + (tok0 + tok) * DM + c * 8) = val;
    }
    // final score partial for this block (deterministic slot per block)
    if (tid < 64) {
        int d = tid >> 3, e = tid & 7;
        int par = d >> 2, r = d & 3;
        float s = 0.f;
        #pragma unroll
        for (int ww = 0; ww < 4; ++ww)
            s += red[(ww * 4 + par) * 33 + r * 8 + e] +
                 red[(ww * 4 + par + 2) * 33 + r * 8 + e];
        scoreacc[(long)blockIdx.x * 64 + tid] = s;
    }
}

// ---------------------------------------------------------------------------
// k_medsoft: per chunk: sum 4 block-partials, *NORMF, lower-median strict
// mask, softmax -> probs[p][8][8].
// ---------------------------------------------------------------------------
__global__ __launch_bounds__(64)
void k_medsoft(const float* __restrict__ scoreacc, float* __restrict__ probs)
{
    __shared__ float sc[64], pl[64];
    const int p = blockIdx.x, tid = threadIdx.x;
    const float* s0 = scoreacc + (long)p * 256;
    sc[tid] = (s0[tid] + s0[64 + tid] + s0[128 + tid] + s0[192 + tid]) * NORMF;
    __syncthreads();
    if (tid < 8) {
        float row[8], st[8];
        #pragma unroll
        for (int e = 0; e < 8; ++e) { row[e] = sc[tid * 8 + e]; st[e] = row[e]; }
        for (int a = 1; a < 8; ++a) {
            float v = st[a]; int b = a - 1;
            while (b >= 0 && st[b] > v) { st[b + 1] = st[b]; --b; }
            st[b + 1] = v;
        }
        float med = st[3];
        float mv[8]; float mx = -3.0e38f;
        #pragma unroll
        for (int e = 0; e < 8; ++e) {
            mv[e] = (row[e] - med > 0.f) ? row[e] : -1e30f;
            mx = fmaxf(mx, mv[e]);
        }
        float z = 0.f, ex[8];
        #pragma unroll
        for (int e = 0; e < 8; ++e) { ex[e] = expf(mv[e] - mx); z += ex[e]; }
        float iz = 1.f / z;
        #pragma unroll
        for (int e = 0; e < 8; ++e) pl[tid * 8 + e] = ex[e] * iz;
    }
    __syncthreads();
    probs[(long)p * 64 + tid] = pl[tid];
}

// ---------------------------------------------------------------------------
// k_ao_scatter: AO = probs @ V-groups (V bf16) -> permuted attn (bf16).
// ---------------------------------------------------------------------------
__global__ __launch_bounds__(256)
void k_ao_scatter(const ushort_t* __restrict__ Vbf,
                  const float* __restrict__ probs,
                  ushort_t* __restrict__ attnbf)
{
    __shared__ float pl[64];
    const int tid = threadIdx.x;
    const int p = blockIdx.x >> 4;
    if (tid < 64) pl[tid] = probs[(long)p * 64 + tid];
    __syncthreads();

    const long w = (long)blockIdx.x * 256 + tid;
    const long t = w >> 4;
    const int  j = (int)(w & 15);
    const int  r = (int)(t & 255);
    const int  g = p >> 5, b = p & 31;

    u16x8 v8 = *(const u16x8*)(Vbf + t * DM + j * 8);
    float vvf[8];
    #pragma unroll
    for (int e = 0; e < 8; ++e) vvf[e] = b2f(v8[e]);
    u16x8 pkt;
    #pragma unroll
    for (int d = 0; d < 8; ++d) {
        float s = 0.f;
        #pragma unroll
        for (int e = 0; e < 8; ++e) s = fmaf(pl[d * 8 + e], vvf[e], s);
        pkt[d] = f2b(s);
    }
    const long tok2 = (long)g * 8192 + r * 32 + j * 2 + (b >> 4);
    *(u16x8*)(attnbf + tok2 * DM + (b & 15) * 8) = pkt;
}

// ---------------------------------------------------------------------------
// k_wo_mfma: h = LN(v + attn@Wo + bo) -> h (f32) and hbf (bf16)
// ---------------------------------------------------------------------------
__global__ __launch_bounds__(256)
void k_wo_mfma(const ushort_t* __restrict__ attnbf,
               const ushort_t* __restrict__ Wot,
               const float* __restrict__ bo,
               const float* __restrict__ vres,
               const float* __restrict__ lng, const float* __restrict__ lnb,
               float* __restrict__ h, ushort_t* __restrict__ hbf)
{
    __shared__ __align__(16) ushort_t Xb[64 * 128];
    __shared__ float pS[256], pQ[256], muS[64], rsS[64];
    const int tid = threadIdx.x;
    const int w = tid >> 6, l = tid & 63;
    const int lr = l & 15, lg = l >> 4;
    const long tok0 = (long)blockIdx.x * 64;

    #pragma unroll
    for (int i = 0; i < 4; ++i) {
        int e = tid + i * 256;
        int tok = e >> 4, c = e & 15;
        u16x8 val = *(const u16x8*)(attnbf + (tok0 + tok) * DM + c * 8);
        *(u16x8*)(Xb + xb_off(tok, c)) = val;
    }

    bf16x8 aw[2][4];
    #pragma unroll
    for (int ot = 0; ot < 2; ++ot)
        #pragma unroll
        for (int ks = 0; ks < 4; ++ks)
            aw[ot][ks] = *(const bf16x8*)(Wot + ((long)((w * 2 + ot) * 4 + ks) * 64 + l) * 8);

    f32x4 bov[2], g4[2], bb4[2];
    #pragma unroll
    for (int ot = 0; ot < 2; ++ot) {
        int oc0 = w * 32 + ot * 16 + lg * 4;
        bov[ot] = *(const f32x4*)(bo + oc0);
        g4[ot]  = *(const f32x4*)(lng + oc0);
        bb4[ot] = *(const f32x4*)(lnb + oc0);
    }
    __syncthreads();

    float vals[4][2][4];
    float sums[4], sqs[4];
    #pragma unroll
    for (int tt = 0; tt < 4; ++tt) {
        f32x4 acc[2] = {(f32x4){0,0,0,0}, (f32x4){0,0,0,0}};
        int tok = tt * 16 + lr;
        #pragma unroll
        for (int ks = 0; ks < 4; ++ks) {
            bf16x8 bfrag = *(const bf16x8*)(Xb + xb_off(tok, ks * 4 + lg));
            acc[0] = mfma16(aw[0][ks], bfrag, acc[0]);
            acc[1] = mfma16(aw[1][ks], bfrag, acc[1]);
        }
        long gtok = tok0 + tok;
        float s = 0.f, q = 0.f;
        #pragma unroll
        for (int ot = 0; ot < 2; ++ot) {
            int oc0 = w * 32 + ot * 16 + lg * 4;
            f32x4 xv = *(const f32x4*)(vres + gtok * DM + oc0);
            #pragma unroll
            for (int r = 0; r < 4; ++r) {
                float vvv = acc[ot][r] + bov[ot][r] + xv[r];
                vals[tt][ot][r] = vvv;
                s += vvv; q = fmaf(vvv, vvv, q);
            }
        }
        sums[tt] = s; sqs[tt] = q;
    }
    #pragma unroll
    for (int tt = 0; tt < 4; ++tt) {
        sums[tt] += __shfl_xor(sums[tt], 16);
        sums[tt] += __shfl_xor(sums[tt], 32);
        sqs[tt]  += __shfl_xor(sqs[tt], 16);
        sqs[tt]  += __shfl_xor(sqs[tt], 32);
    }
    #pragma unroll
    for (int tt = 0; tt < 4; ++tt)
        if (lg == tt) { pS[(w * 4 + tt) * 16 + lr] = sums[tt];
                        pQ[(w * 4 + tt) * 16 + lr] = sqs[tt]; }
    __syncthreads();
    if (tid < 64) {
        float s = pS[tid] + pS[64 + tid] + pS[128 + tid] + pS[192 + tid];
        float q = pQ[tid] + pQ[64 + tid] + pQ[128 + tid] + pQ[192 + tid];
        float mu = s * 0.0078125f;
        float var = q * 0.0078125f - mu * mu;
        muS[tid] = mu;
        rsS[tid] = rsqrtf(var + 1e-5f);
    }
    __syncthreads();
    #pragma unroll
    for (int tt = 0; tt < 4; ++tt) {
        int tokl = tt * 16 + lr;
        long gtok = tok0 + tokl;
        float mu = muS[tokl], rs = rsS[tokl];
        #pragma unroll
        for (int ot = 0; ot < 2; ++ot) {
            int oc0 = w * 32 + ot * 16 + lg * 4;
            f32x4 o;
            #pragma unroll
            for (int r = 0; r < 4; ++r)
                o[r] = (vals[tt][ot][r] - mu) * rs * g4[ot][r] + bb4[ot][r];
            *(f32x4*)(h + gtok * DM + oc0) = o;
            u32x2 pk = {pack2(o[0], o[1]), pack2(o[2], o[3])};
            *(u32x2*)(hbf + gtok * DM + oc0) = pk;
        }
    }
}

// ---------------------------------------------------------------------------
// k_ffn_mfma: out = LN(h + gelu(h@W1+b1)@W2 + b2) + v   [MFMA, 2x256 slices]
// ---------------------------------------------------------------------------
__global__ __launch_bounds__(256, 3)
void k_ffn_mfma(const ushort_t* __restrict__ hbf,
                const float* __restrict__ hres,
                const ushort_t* __restrict__ W1t,
                const float* __restrict__ b1,
                const ushort_t* __restrict__ W2t,
                const float* __restrict__ b2,
                const float* __restrict__ lng, const float* __restrict__ lnb,
                const float* __restrict__ vres, float* __restrict__ out)
{
    __shared__ __align__(16) ushort_t Xb[64 * 128];     // 16 KB
    __shared__ __align__(16) ushort_t Hid[64 * 256];    // 32 KB
    __shared__ float pS[256], pQ[256], muS[64], rsS[64];

    const int tid = threadIdx.x;
    const int w = tid >> 6, l = tid & 63;
    const int lr = l & 15, lg = l >> 4;
    const long tok0 = (long)blockIdx.x * 64;

    #pragma unroll
    for (int i = 0; i < 4; ++i) {
        int e = tid + i * 256;
        int tok = e >> 4, c = e & 15;
        u16x8 val = *(const u16x8*)(hbf + (tok0 + tok) * DM + c * 8);
        *(u16x8*)(Xb + xb_off(tok, c)) = val;
    }

    f32x4 oacc[4][2];
    #pragma unroll
    for (int tt = 0; tt < 4; ++tt) {
        oacc[tt][0] = (f32x4){0,0,0,0};
        oacc[tt][1] = (f32x4){0,0,0,0};
    }
    __syncthreads();

    for (int sl = 0; sl < 2; ++sl) {
        // ---- stage 1: Hid-slice = gelu(X@W1_sl + b1_sl), transposed D ----
        bf16x8 a1[4][4];
        #pragma unroll
        for (int ht = 0; ht < 4; ++ht)
            #pragma unroll
            for (int ks = 0; ks < 4; ++ks)
                a1[ht][ks] = *(const bf16x8*)(W1t +
                    ((long)(((sl * 16 + w * 4 + ht) * 4) + ks) * 64 + l) * 8);
        f32x4 b1v[4];
        #pragma unroll
        for (int ht = 0; ht < 4; ++ht)
            b1v[ht] = *(const f32x4*)(b1 + sl * 256 + w * 64 + ht * 16 + lg * 4);

        #pragma unroll
        for (int tt = 0; tt < 4; ++tt) {
            f32x4 acc[4];
            #pragma unroll
            for (int ht = 0; ht < 4; ++ht) acc[ht] = (f32x4){0,0,0,0};
            int tok = tt * 16 + lr;
            #pragma unroll
            for (int ks = 0; ks < 4; ++ks) {
                bf16x8 bfrag = *(const bf16x8*)(Xb + xb_off(tok, ks * 4 + lg));
                #pragma unroll
                for (int ht = 0; ht < 4; ++ht)
                    acc[ht] = mfma16(a1[ht][ks], bfrag, acc[ht]);
            }
            #pragma unroll
            for (int ht = 0; ht < 4; ++ht) {
                float g[4];
                #pragma unroll
                for (int r = 0; r < 4; ++r)
                    g[r] = gelu_f(acc[ht][r] + b1v[ht][r]);
                int hc0 = w * 64 + ht * 16 + lg * 4;
                int ch = hc0 >> 3;
                int cz = (ch & 24) | ((ch ^ tok) & 7);
                u32x2 pk = {pack2(g[0], g[1]), pack2(g[2], g[3])};
                *(u32x2*)(Hid + tok * 256 + cz * 8 + (hc0 & 7)) = pk;
            }
        }
        __syncthreads();

        // ---- stage 2: accumulate slice into oacc ----
        bf16x8 a2[2][8];
        #pragma unroll
        for (int ot = 0; ot < 2; ++ot)
            #pragma unroll
            for (int kl = 0; kl < 8; ++kl)
                a2[ot][kl] = *(const bf16x8*)(W2t +
                    ((long)((w * 2 + ot) * 16 + sl * 8 + kl) * 64 + l) * 8);

        #pragma unroll
        for (int tt = 0; tt < 4; ++tt) {
            int tok = tt * 16 + lr;
            #pragma unroll
            for (int kl = 0; kl < 8; ++kl) {
                bf16x8 bfrag = *(const bf16x8*)(Hid + h2_off(tok, kl * 4 + lg));
                oacc[tt][0] = mfma16(a2[0][kl], bfrag, oacc[tt][0]);
                oacc[tt][1] = mfma16(a2[1][kl], bfrag, oacc[tt][1]);
            }
        }
        __syncthreads();
    }

    // ---- epilogue: LN(h + ffn) + v ----
    f32x4 b2v[2], g4[2], bb4[2];
    #pragma unroll
    for (int ot = 0; ot < 2; ++ot) {
        int oc0 = w * 32 + ot * 16 + lg * 4;
        b2v[ot] = *(const f32x4*)(b2 + oc0);
        g4[ot]  = *(const f32x4*)(lng + oc0);
        bb4[ot] = *(const f32x4*)(lnb + oc0);
    }
    float vals[4][2][4];
    float sums[4], sqs[4];
    #pragma unroll
    for (int tt = 0; tt < 4; ++tt) {
        int tok = tt * 16 + lr;
        long gtok = tok0 + tok;
        float s = 0.f, q = 0.f;
        #pragma unroll
        for (int ot = 0; ot < 2; ++ot) {
            int oc0 = w * 32 + ot * 16 + lg * 4;
            f32x4 xr = *(const f32x4*)(hres + gtok * DM + oc0);
            #pragma unroll
            for (int r = 0; r < 4; ++r) {
                float vvv = oacc[tt][ot][r] + b2v[ot][r] + xr[r];
                vals[tt][ot][r] = vvv;
                s += vvv; q = fmaf(vvv, vvv, q);
            }
        }
        sums[tt] = s; sqs[tt] = q;
    }
    #pragma unroll
    for (int tt = 0; tt < 4; ++tt) {
        sums[tt] += __shfl_xor(sums[tt], 16);
        sums[tt] += __shfl_xor(sums[tt], 32);
        sqs[tt]  += __shfl_xor(sqs[tt], 16);
        sqs[tt]  += __shfl_xor(sqs[tt], 32);
    }
    #pragma unroll
    for (int tt = 0; tt < 4; ++tt)
        if (lg == tt) { pS[(w * 4 + tt) * 16 + lr] = sums[tt];
                        pQ[(w * 4 + tt) * 16 + lr] = sqs[tt]; }
    __syncthreads();
    if (tid < 64) {
        float s = pS[tid] + pS[64 + tid] + pS[128 + tid] + pS[192 + tid];
        float q = pQ[tid] + pQ[64 + tid] + pQ[128 + tid] + pQ[192 + tid];
        float mu = s * 0.0078125f;
        float var = q * 0.0078125f - mu * mu;
        muS[tid] = mu;
        rsS[tid] = rsqrtf(var + 1e-5f);
    }
    __syncthreads();
    #pragma unroll
    for (int tt = 0; tt < 4; ++tt) {
        int tokl = tt * 16 + lr;
        long gtok = tok0 + tokl;
        float mu = muS[tokl], rs = rsS[tokl];
        #pragma unroll
        for (int ot = 0; ot < 2; ++ot) {
            int oc0 = w * 32 + ot * 16 + lg * 4;
            f32x4 vv4 = *(const f32x4*)(vres + gtok * DM + oc0);
            f32x4 o;
            #pragma unroll
            for (int r = 0; r < 4; ++r)
                o[r] = (vals[tt][ot][r] - mu) * rs * g4[ot][r] + bb4[ot][r] + vv4[r];
            *(f32x4*)(out + gtok * DM + oc0) = o;
        }
    }
}

// ---------------------------------------------------------------------------
extern "C" void kernel_launch(void* const* d_in, const int* in_sizes, int n_in,
                              void* d_out, int out_size, void* d_ws, size_t ws_size,
                              hipStream_t stream)
{
    const float* q   = (const float*)d_in[0];
    const float* v   = (const float*)d_in[1];
    const float* Wq  = (const float*)d_in[2];
    const float* bq  = (const float*)d_in[3];
    const float* Wk  = (const float*)d_in[4];
    const float* bk  = (const float*)d_in[5];
    const float* Wv  = (const float*)d_in[6];
    const float* bv  = (const float*)d_in[7];
    const float* Wo  = (const float*)d_in[8];
    const float* bo  = (const float*)d_in[9];
    const float* lng = (const float*)d_in[10];
    const float* lnb = (const float*)d_in[11];
    const float* W1  = (const float*)d_in[12];
    const float* b1  = (const float*)d_in[13];
    const float* W2  = (const float*)d_in[14];
    const float* b2  = (const float*)d_in[15];
    float* out = (float*)d_out;

    char* W = (char*)d_ws;
    ushort_t* Vbf      = (ushort_t*)(W);                  // 32 MB
    ushort_t* attnbf   = (ushort_t*)(W + 33554432);       // 32 MB
    ushort_t* hbf      = (ushort_t*)(W + 67108864);       // 32 MB
    float*    hres     = (float*)(W + 100663296);         // 64 MB
    float*    scoreacc = (float*)(W + 167772160);         // 512 KB
    float*    probs    = (float*)(W + 168296448);         // 128 KB
    char* wbase = W + 168427520;
    ushort_t* Wqh = (ushort_t*)(wbase);
    ushort_t* Wql = (ushort_t*)(wbase + 32768);
    ushort_t* Wkh = (ushort_t*)(wbase + 65536);
    ushort_t* Wkl = (ushort_t*)(wbase + 98304);
    ushort_t* Wvh = (ushort_t*)(wbase + 131072);
    ushort_t* Wvl = (ushort_t*)(wbase + 163840);
    ushort_t* W1t = (ushort_t*)(wbase + 196608);          // 128 KB
    ushort_t* W2t = (ushort_t*)(wbase + 327680);          // 128 KB
    ushort_t* Wot = (ushort_t*)(wbase + 458752);          // 32 KB

    dim3 blk(256);
    k_wcvt<<<96, blk, 0, stream>>>(W1, W2, Wo, Wq, Wk, Wv,
                                   W1t, W2t, Wot, Wqh, Wql, Wkh, Wkl, Wvh, Wvl);
    k_qkvs<<<2048, blk, 0, stream>>>(q, v, Wqh, Wql, Wkh, Wkl, Wvh, Wvl,
                                     bq, bk, bv, Vbf, scoreacc);
    k_medsoft<<<512, dim3(64), 0, stream>>>(scoreacc, probs);
    k_ao_scatter<<<8192, blk, 0, stream>>>(Vbf, probs, attnbf);
    k_wo_mfma<<<2048, blk, 0, stream>>>(attnbf, Wot, bo, v, lng, lnb, hres, hbf);
    k_ffn_mfma<<<2048, blk, 0, stream>>>(hbf, hres, W1t, b1, W2t, b2, lng, lnb, v, out);
}